// Round 8
// baseline (57.494 us; speedup 1.0000x reference)
//
#include <hip/hip_runtime.h>

#define DIM   4096
#define BATCH 8192
// One wave per row, 4 rows per 256-thread block. Thread lane holds
// e = 256j + 4*lane + i (j=0..15, i=0..3) -> 16 float4, whole row in wave.
// Layer L pairs e with e^(1<<L); coeff index c = (4096 - (4096>>L)) + (e >> (L+1)).
//   L0..L1  : within float4 (i axis)       — register FMAs           [R0-validated]
//   L2..L7  : lane xor 1,2,4,8,16,32       — DPP quad_perm (1,2), ds_swizzle (4,16),
//                                            DPP row_ror:8 (8), permlane32_swap (32)
//                                            [R6-validated pxor]
//   L8..L11 : register index j dist 1,2,4,8 — register FMAs, wave-uniform coeffs
// ZERO LDS storage, ZERO barriers. Stores nontemporal (out never re-read).
// R1/R3 lesson: no min-waves launch bound; spill tell = WRITE_SIZE > 131072 KB.

#if defined(__has_builtin)
#  if __has_builtin(__builtin_amdgcn_permlane32_swap)
#    define HAVE_PL32 1
#  endif
#endif
#ifndef HAVE_PL32
#  define HAVE_PL32 0
#endif

typedef float f32x4_v __attribute__((ext_vector_type(4)));

__device__ __forceinline__ void store_nt4(float4* p, const float4& v) {
    f32x4_v t; t.x = v.x; t.y = v.y; t.z = v.z; t.w = v.w;
    __builtin_nontemporal_store(t, reinterpret_cast<f32x4_v*>(p));
}

__device__ __forceinline__ void rot2(float& lo, float& hi, float a, float b) {
    float l = lo, h = hi;
    lo = fmaf(a, l,  b * h);   // top =  a*x0 + b*x1
    hi = fmaf(a, h, -b * l);   // bot = -b*x0 + a*x1
}
__device__ __forceinline__ void rot4(float4& lo, float4& hi, float a, float b) {
    rot2(lo.x, hi.x, a, b); rot2(lo.y, hi.y, a, b);
    rot2(lo.z, hi.z, a, b); rot2(lo.w, hi.w, a, b);
}

template<bool PACKED>
__device__ __forceinline__ float2 coef(const float* __restrict__ af,
                                       const float* __restrict__ bf,
                                       const float2* __restrict__ ab, int c) {
    if constexpr (PACKED) return ab[c];
    else                  return make_float2(af[c], bf[c]);
}

// Cross-lane xor-M partner fetch on the fastest pipe per M (R6-validated).
template<int M>
__device__ __forceinline__ float pxor(float x, bool hi) {
    int xi = __float_as_int(x);
    if constexpr (M == 1)        // quad_perm [1,0,3,2]
        return __int_as_float(__builtin_amdgcn_update_dpp(0, xi, 0xB1, 0xF, 0xF, true));
    else if constexpr (M == 2)   // quad_perm [2,3,0,1]
        return __int_as_float(__builtin_amdgcn_update_dpp(0, xi, 0x4E, 0xF, 0xF, true));
    else if constexpr (M == 4)   // ds_swizzle BitMode xor 4
        return __int_as_float(__builtin_amdgcn_ds_swizzle(xi, 0x101F));
    else if constexpr (M == 8)   // row_ror:8 within row-of-16 == xor 8
        return __int_as_float(__builtin_amdgcn_update_dpp(0, xi, 0x128, 0xF, 0xF, true));
    else if constexpr (M == 16)  // ds_swizzle BitMode xor 16 (within 32-halves)
        return __int_as_float(__builtin_amdgcn_ds_swizzle(xi, 0x401F));
    else {                       // M == 32
#if HAVE_PL32
        unsigned xu = (unsigned)xi;
        auto r = __builtin_amdgcn_permlane32_swap(xu, xu, false, false);
        return __uint_as_float(hi ? r[0] : r[1]);
#else
        return __shfl_xor(x, 32, 64);
#endif
    }
}

// c = BASE + (j<<JSHIFT) + (lane>>LANESHIFT)  (R0-validated index math)
template<int M, int BASE, int JSHIFT, int LANESHIFT, bool PACKED>
__device__ __forceinline__ void shuf_layer(float4* v, int lane,
                                           const float* __restrict__ af,
                                           const float* __restrict__ bf,
                                           const float2* __restrict__ ab) {
    const bool hi = (lane & M) != 0;
    #pragma unroll
    for (int j = 0; j < 16; ++j) {
        const int c = BASE + (j << JSHIFT) + (lane >> LANESHIFT);
        float2 q = coef<PACKED>(af, bf, ab, c);
        const float sb = hi ? -q.y : q.y;   // top: +b*partner ; bot: -b*partner
        v[j].x = fmaf(q.x, v[j].x, sb * pxor<M>(v[j].x, hi));
        v[j].y = fmaf(q.x, v[j].y, sb * pxor<M>(v[j].y, hi));
        v[j].z = fmaf(q.x, v[j].z, sb * pxor<M>(v[j].z, hi));
        v[j].w = fmaf(q.x, v[j].w, sb * pxor<M>(v[j].w, hi));
    }
}

template<bool PACKED>
__global__ __launch_bounds__(256)
void bfly_kernel(const float* __restrict__ x,
                 const float* __restrict__ af,
                 const float* __restrict__ bf,
                 const float2* __restrict__ ab,
                 float* __restrict__ out) {
    const int lane = threadIdx.x & 63;
    const int wv   = threadIdx.x >> 6;
    const size_t row = (size_t)blockIdx.x * 4 + wv;

    const float4* __restrict__ xr = reinterpret_cast<const float4*>(x + row * DIM);
    float4* __restrict__ orow     = reinterpret_cast<float4*>(out + row * DIM);

    float4 v[16];
    #pragma unroll
    for (int j = 0; j < 16; ++j) v[j] = xr[64 * j + lane];

    // ---- L0 (bs=1): pairs (x,y),(z,w); c0 = 128j + 2*lane (+1) ----
    #pragma unroll
    for (int j = 0; j < 16; ++j) {
        float a0, b0, a1, b1;
        if constexpr (PACKED) {
            float4 q = reinterpret_cast<const float4*>(ab)[64 * j + lane]; // (a0,b0,a1,b1)
            a0 = q.x; b0 = q.y; a1 = q.z; b1 = q.w;
        } else {
            float2 aa = *reinterpret_cast<const float2*>(af + 128 * j + 2 * lane);
            float2 bb = *reinterpret_cast<const float2*>(bf + 128 * j + 2 * lane);
            a0 = aa.x; b0 = bb.x; a1 = aa.y; b1 = bb.y;
        }
        rot2(v[j].x, v[j].y, a0, b0);
        rot2(v[j].z, v[j].w, a1, b1);
    }

    // ---- L1 (bs=2): pairs (x,z),(y,w); c = 2048 + 64j + lane ----
    #pragma unroll
    for (int j = 0; j < 16; ++j) {
        float2 q = coef<PACKED>(af, bf, ab, 2048 + 64 * j + lane);
        rot2(v[j].x, v[j].z, q.x, q.y);
        rot2(v[j].y, v[j].w, q.x, q.y);
    }

    // ---- L2..L7: cross-lane layers on VALU/DPP where possible ----
    shuf_layer< 1, 3072, 5, 1, PACKED>(v, lane, af, bf, ab);   // bs=4
    shuf_layer< 2, 3584, 4, 2, PACKED>(v, lane, af, bf, ab);   // bs=8
    shuf_layer< 4, 3840, 3, 3, PACKED>(v, lane, af, bf, ab);   // bs=16
    shuf_layer< 8, 3968, 2, 4, PACKED>(v, lane, af, bf, ab);   // bs=32
    shuf_layer<16, 4032, 1, 5, PACKED>(v, lane, af, bf, ab);   // bs=64
    shuf_layer<32, 4064, 0, 6, PACKED>(v, lane, af, bf, ab);   // bs=128

    // ---- L8 (bs=256): pairs (j, j+1), j even; c = 4080 + (j>>1) ----
    #pragma unroll
    for (int j = 0; j < 16; j += 2) {
        float2 q = coef<PACKED>(af, bf, ab, 4080 + (j >> 1));
        rot4(v[j], v[j + 1], q.x, q.y);
    }
    // ---- L9 (bs=512): pairs (j, j+2), j in {0,1,4,5,8,9,12,13}; c = 4088 + (j>>2) ----
    #pragma unroll
    for (int jj = 0; jj < 8; ++jj) {
        const int j = ((jj >> 1) << 2) | (jj & 1);
        float2 q = coef<PACKED>(af, bf, ab, 4088 + (j >> 2));
        rot4(v[j], v[j + 2], q.x, q.y);
    }
    // ---- L10 (bs=1024): pairs (j, j+4), j in {0..3, 8..11}; c = 4092 + (j>>3) ----
    #pragma unroll
    for (int jj = 0; jj < 8; ++jj) {
        const int j = ((jj >> 2) << 3) | (jj & 3);
        float2 q = coef<PACKED>(af, bf, ab, 4092 + (j >> 3));
        rot4(v[j], v[j + 4], q.x, q.y);
    }
    // ---- L11 (bs=2048): pairs (j, j+8), j=0..7; c = 4094 ----
    {
        float2 q = coef<PACKED>(af, bf, ab, 4094);
        #pragma unroll
        for (int j = 0; j < 8; ++j) rot4(v[j], v[j + 8], q.x, q.y);
    }

    // ---- Store: nontemporal, coalesced 16B/lane ----
    #pragma unroll
    for (int j = 0; j < 16; ++j) store_nt4(&orow[64 * j + lane], v[j]);
}

__global__ void pack_ab_kernel(const float* __restrict__ af,
                               const float* __restrict__ bf,
                               float2* __restrict__ ab) {
    int i = blockIdx.x * 256 + threadIdx.x;
    if (i < DIM - 1) ab[i] = make_float2(af[i], bf[i]);
}

extern "C" void kernel_launch(void* const* d_in, const int* in_sizes, int n_in,
                              void* d_out, int out_size, void* d_ws, size_t ws_size,
                              hipStream_t stream) {
    const float* x  = (const float*)d_in[0];
    const float* af = (const float*)d_in[1];
    const float* bf = (const float*)d_in[2];
    float* out      = (float*)d_out;

    const bool packed = (d_ws != nullptr) && (ws_size >= (size_t)(DIM - 1) * sizeof(float2));
    if (packed) {
        float2* ab = (float2*)d_ws;
        hipLaunchKernelGGL(pack_ab_kernel, dim3(16), dim3(256), 0, stream, af, bf, ab);
        hipLaunchKernelGGL((bfly_kernel<true>),  dim3(BATCH / 4), dim3(256), 0, stream,
                           x, af, bf, ab, out);
    } else {
        hipLaunchKernelGGL((bfly_kernel<false>), dim3(BATCH / 4), dim3(256), 0, stream,
                           x, af, bf, nullptr, out);
    }
}

// Round 9
// 55.118 us; speedup vs baseline: 1.0431x; 1.0431x over previous
//
#include <hip/hip_runtime.h>

#define DIM   4096
#define BATCH 8192
// One row per 256-thread block (R2/R6-validated structure). Wave q owns quarter
// [1024q, 1024q+1024); thread lane holds e = 1024q + 256j + 4*lane + i (j,i=0..3).
// Layer L pairs e with e^(1<<L); coeff index c = (4096 - (4096>>L)) + (e >> (L+1)).
//   L0..L1  : within float4 (i axis)        — register FMAs
//   L2..L7  : lane xor 1,2,4,8,16,32        — quad_perm DPP (1,2), ds_swizzle (4),
//                                             row_ror:8 DPP (8), permlane16_swap (16),
//                                             permlane32_swap (32)
//             -> only xor4 remains on the shared per-CU LDS pipe.
//   L8..L9  : register index j distance 1,2 — register FMAs
//   L10+L11 : cross-wave, FUSED 4-source combine (R3/R6-verified), ONE barrier.
// Stores nontemporal (out never re-read; keep x resident in L2/L3).
// R1/R3 lesson: VGPR cap must exceed working set — (256,7) caps at ~73, compiler
// lands at ~28-32. Spill tell = WRITE_SIZE > 131072 KB.

#if defined(__has_builtin)
#  if __has_builtin(__builtin_amdgcn_permlane32_swap)
#    define HAVE_PL32 1
#  endif
#  if __has_builtin(__builtin_amdgcn_permlane16_swap)
#    define HAVE_PL16 1
#  endif
#endif
#ifndef HAVE_PL32
#  define HAVE_PL32 0
#endif
#ifndef HAVE_PL16
#  define HAVE_PL16 0
#endif

typedef float f32x4_v __attribute__((ext_vector_type(4)));

__device__ __forceinline__ void store_nt4(float4* p, const float4& v) {
    f32x4_v t; t.x = v.x; t.y = v.y; t.z = v.z; t.w = v.w;
    __builtin_nontemporal_store(t, reinterpret_cast<f32x4_v*>(p));
}

__device__ __forceinline__ void rot2(float& lo, float& hi, float a, float b) {
    float l = lo, h = hi;
    lo = fmaf(a, l,  b * h);   // top =  a*x0 + b*x1
    hi = fmaf(a, h, -b * l);   // bot = -b*x0 + a*x1
}

template<bool PACKED>
__device__ __forceinline__ float2 coef(const float* __restrict__ af,
                                       const float* __restrict__ bf,
                                       const float2* __restrict__ ab, int c) {
    if constexpr (PACKED) return ab[c];
    else                  return make_float2(af[c], bf[c]);
}

// Cross-lane xor-M partner fetch on the fastest pipe per M.
// pl32 semantics validated R6/R7; pl16 is the exact 16-row analog:
//   swap(old,src) with old=src=x gives r0 = rows{x.r0,x.r0,x.r2,x.r2},
//   r1 = rows{x.r1,x.r1,x.r3,x.r3}; partner(x, xor16) = (lane&16) ? r0 : r1.
template<int M>
__device__ __forceinline__ float pxor(float x, bool hi) {
    int xi = __float_as_int(x);
    if constexpr (M == 1)        // quad_perm [1,0,3,2]
        return __int_as_float(__builtin_amdgcn_update_dpp(0, xi, 0xB1, 0xF, 0xF, true));
    else if constexpr (M == 2)   // quad_perm [2,3,0,1]
        return __int_as_float(__builtin_amdgcn_update_dpp(0, xi, 0x4E, 0xF, 0xF, true));
    else if constexpr (M == 4)   // ds_swizzle BitMode xor 4 (R6-validated)
        return __int_as_float(__builtin_amdgcn_ds_swizzle(xi, 0x101F));
    else if constexpr (M == 8)   // row_ror:8 within row-of-16 == xor 8 (R6-validated)
        return __int_as_float(__builtin_amdgcn_update_dpp(0, xi, 0x128, 0xF, 0xF, true));
    else if constexpr (M == 16) {
#if HAVE_PL16
        unsigned xu = (unsigned)xi;
        auto r = __builtin_amdgcn_permlane16_swap(xu, xu, false, false);
        return __uint_as_float(hi ? r[0] : r[1]);
#else
        return __int_as_float(__builtin_amdgcn_ds_swizzle(xi, 0x401F));
#endif
    } else {                     // M == 32 (R6-validated)
#if HAVE_PL32
        unsigned xu = (unsigned)xi;
        auto r = __builtin_amdgcn_permlane32_swap(xu, xu, false, false);
        return __uint_as_float(hi ? r[0] : r[1]);
#else
        return __shfl_xor(x, 32, 64);
#endif
    }
}

template<int M, int JSH, int LSH, bool PACKED>
__device__ __forceinline__ void shuf_layer(float4 (&v)[4], int lane, int base,
                                           const float* __restrict__ af,
                                           const float* __restrict__ bf,
                                           const float2* __restrict__ ab) {
    const bool hi = (lane & M) != 0;
    #pragma unroll
    for (int j = 0; j < 4; ++j) {
        const int c = base + (j << JSH) + (lane >> LSH);
        float2 p = coef<PACKED>(af, bf, ab, c);
        const float sb = hi ? -p.y : p.y;   // top: +b*partner ; bot: -b*partner
        v[j].x = fmaf(p.x, v[j].x, sb * pxor<M>(v[j].x, hi));
        v[j].y = fmaf(p.x, v[j].y, sb * pxor<M>(v[j].y, hi));
        v[j].z = fmaf(p.x, v[j].z, sb * pxor<M>(v[j].z, hi));
        v[j].w = fmaf(p.x, v[j].w, sb * pxor<M>(v[j].w, hi));
    }
}

template<bool PACKED>
__global__ __launch_bounds__(256, 7)
void bfly_kernel(const float* __restrict__ x,
                 const float* __restrict__ af,
                 const float* __restrict__ bf,
                 const float2* __restrict__ ab,
                 float* __restrict__ out) {
    const int lane = threadIdx.x & 63;
    const int q    = threadIdx.x >> 6;     // wave index = row quarter
    const size_t row = blockIdx.x;

    const float4* __restrict__ xr = reinterpret_cast<const float4*>(x + row * DIM) + q * 256;
    float4* __restrict__ orow     = reinterpret_cast<float4*>(out + row * DIM) + q * 256;

    __shared__ float4 xch[4][4][64];   // [wave][j][lane] = 16 KB

    float4 v[4];
    #pragma unroll
    for (int j = 0; j < 4; ++j) v[j] = xr[64 * j + lane];

    // ---- L0 (bs=1): pairs (x,y),(z,w); c0 = 512q + 128j + 2*lane, c0+1 ----
    #pragma unroll
    for (int j = 0; j < 4; ++j) {
        float a0, b0, a1, b1;
        if constexpr (PACKED) {
            float4 p = reinterpret_cast<const float4*>(ab)[q * 256 + 64 * j + lane];
            a0 = p.x; b0 = p.y; a1 = p.z; b1 = p.w;
        } else {
            const int c = 512 * q + 128 * j + 2 * lane;
            float2 aa = *reinterpret_cast<const float2*>(af + c);
            float2 bb = *reinterpret_cast<const float2*>(bf + c);
            a0 = aa.x; b0 = bb.x; a1 = aa.y; b1 = bb.y;
        }
        rot2(v[j].x, v[j].y, a0, b0);
        rot2(v[j].z, v[j].w, a1, b1);
    }

    // ---- L1 (bs=2): pairs (x,z),(y,w); c = 2048 + 256q + 64j + lane ----
    #pragma unroll
    for (int j = 0; j < 4; ++j) {
        float2 p = coef<PACKED>(af, bf, ab, 2048 + 256 * q + 64 * j + lane);
        rot2(v[j].x, v[j].z, p.x, p.y);
        rot2(v[j].y, v[j].w, p.x, p.y);
    }

    // ---- L2..L7: cross-lane layers (DPP / swizzle / permlane) ----
    shuf_layer< 1, 5, 1, PACKED>(v, lane, 3072 + 128 * q, af, bf, ab);  // bs=4
    shuf_layer< 2, 4, 2, PACKED>(v, lane, 3584 +  64 * q, af, bf, ab);  // bs=8
    shuf_layer< 4, 3, 3, PACKED>(v, lane, 3840 +  32 * q, af, bf, ab);  // bs=16
    shuf_layer< 8, 2, 4, PACKED>(v, lane, 3968 +  16 * q, af, bf, ab);  // bs=32
    shuf_layer<16, 1, 5, PACKED>(v, lane, 4032 +   8 * q, af, bf, ab);  // bs=64
    shuf_layer<32, 0, 6, PACKED>(v, lane, 4064 +   4 * q, af, bf, ab);  // bs=128

    // ---- L8 (bs=256): pairs (0,1),(2,3); c = 4080 + 2q + k ----
    #pragma unroll
    for (int k = 0; k < 2; ++k) {
        float2 p = coef<PACKED>(af, bf, ab, 4080 + 2 * q + k);
        rot2(v[2*k].x, v[2*k+1].x, p.x, p.y);
        rot2(v[2*k].y, v[2*k+1].y, p.x, p.y);
        rot2(v[2*k].z, v[2*k+1].z, p.x, p.y);
        rot2(v[2*k].w, v[2*k+1].w, p.x, p.y);
    }
    // ---- L9 (bs=512): pairs (0,2),(1,3); c = 4088 + q ----
    {
        float2 p = coef<PACKED>(af, bf, ab, 4088 + q);
        #pragma unroll
        for (int j = 0; j < 2; ++j) {
            rot2(v[j].x, v[j+2].x, p.x, p.y);
            rot2(v[j].y, v[j+2].y, p.x, p.y);
            rot2(v[j].z, v[j+2].z, p.x, p.y);
            rot2(v[j].w, v[j+2].w, p.x, p.y);
        }
    }

    // ---- L10+L11 fused: one 4-source combine across waves, ONE barrier ----
    // (R3/R6-verified algebra.) u = w0*v + w1*v(q^1) + w2*v(q^2) + w3*v(q^3).
    {
        float2 c0 = coef<PACKED>(af, bf, ab, 4092);   // (a,b) for e11=0
        float2 c1 = coef<PACKED>(af, bf, ab, 4093);   // (a,b) for e11=1
        float2 c2 = coef<PACKED>(af, bf, ab, 4094);   // (A,B)
        const int h11 = q >> 1, h10 = q & 1;
        const float aO = h11 ? c1.x : c0.x, bO = h11 ? c1.y : c0.y;
        const float aX = h11 ? c0.x : c1.x, bX = h11 ? c0.y : c1.y;
        const float phX = h11 ? -c2.y : c2.y;
        const float w0 = c2.x * aO;
        const float w1 = c2.x * (h10 ? -bO : bO);
        const float w2 = phX * aX;
        const float w3 = phX * (h10 ? -bX : bX);
        const int q1 = q ^ 1, q2 = q ^ 2, q3 = q ^ 3;

        #pragma unroll
        for (int j = 0; j < 4; ++j) xch[q][j][lane] = v[j];
        __syncthreads();
        #pragma unroll
        for (int j = 0; j < 4; ++j) {
            float4 e1 = xch[q1][j][lane];
            float4 e2 = xch[q2][j][lane];
            float4 e3 = xch[q3][j][lane];
            float4 a;
            a.x = fmaf(w3, e3.x, fmaf(w2, e2.x, fmaf(w1, e1.x, w0 * v[j].x)));
            a.y = fmaf(w3, e3.y, fmaf(w2, e2.y, fmaf(w1, e1.y, w0 * v[j].y)));
            a.z = fmaf(w3, e3.z, fmaf(w2, e2.z, fmaf(w1, e1.z, w0 * v[j].z)));
            a.w = fmaf(w3, e3.w, fmaf(w2, e2.w, fmaf(w1, e1.w, w0 * v[j].w)));
            v[j] = a;
        }
    }

    // ---- Store: nontemporal, coalesced 16B/lane ----
    #pragma unroll
    for (int j = 0; j < 4; ++j) store_nt4(&orow[64 * j + lane], v[j]);
}

__global__ void pack_ab_kernel(const float* __restrict__ af,
                               const float* __restrict__ bf,
                               float2* __restrict__ ab) {
    int i = blockIdx.x * 256 + threadIdx.x;
    if (i < DIM - 1) ab[i] = make_float2(af[i], bf[i]);
}

extern "C" void kernel_launch(void* const* d_in, const int* in_sizes, int n_in,
                              void* d_out, int out_size, void* d_ws, size_t ws_size,
                              hipStream_t stream) {
    const float* x  = (const float*)d_in[0];
    const float* af = (const float*)d_in[1];
    const float* bf = (const float*)d_in[2];
    float* out      = (float*)d_out;

    const bool packed = (d_ws != nullptr) && (ws_size >= (size_t)(DIM - 1) * sizeof(float2));
    if (packed) {
        float2* ab = (float2*)d_ws;
        hipLaunchKernelGGL(pack_ab_kernel, dim3(16), dim3(256), 0, stream, af, bf, ab);
        hipLaunchKernelGGL((bfly_kernel<true>),  dim3(BATCH), dim3(256), 0, stream,
                           x, af, bf, ab, out);
    } else {
        hipLaunchKernelGGL((bfly_kernel<false>), dim3(BATCH), dim3(256), 0, stream,
                           x, af, bf, nullptr, out);
    }
}

// Round 10
// 47.949 us; speedup vs baseline: 1.1991x; 1.1495x over previous
//
#include <hip/hip_runtime.h>

#define DIM   4096
#define BATCH 8192
// One row per 256-thread block (R2/R6/R8-validated structure). Wave q owns quarter
// [1024q, 1024q+1024); thread lane holds e = 1024q + 256j + 4*lane + i (j,i=0..3).
// Layer L pairs e with e^(1<<L); coeff index c = (4096 - (4096>>L)) + (e >> (L+1)).
//   L0..L1  : within float4 (i axis)        — register FMAs
//   L2..L7  : lane xor 1,2,4,8,16,32        — quad_perm DPP (1,2), ds_swizzle (4),
//                                             row_ror:8 DPP (8), permlane16_swap (16),
//                                             permlane32_swap (32)   [all HW-validated]
//   L8..L9  : register index j distance 1,2 — register FMAs, scalar (s_load) coeffs
//   L10+L11 : cross-wave, FUSED 4-source combine (R3/R6-verified), ONE barrier.
// R9 changes vs R8: no pack dispatch (read af/bf directly — removes a graph-serialized
// kernel); readfirstlane on wave-uniform coeff indices (L7/L8/L9) -> s_load path.
// Stores nontemporal (out never re-read). Spill tell = WRITE_SIZE > 131072 KB.

#if defined(__has_builtin)
#  if __has_builtin(__builtin_amdgcn_permlane32_swap)
#    define HAVE_PL32 1
#  endif
#  if __has_builtin(__builtin_amdgcn_permlane16_swap)
#    define HAVE_PL16 1
#  endif
#endif
#ifndef HAVE_PL32
#  define HAVE_PL32 0
#endif
#ifndef HAVE_PL16
#  define HAVE_PL16 0
#endif

typedef float f32x4_v __attribute__((ext_vector_type(4)));

__device__ __forceinline__ void store_nt4(float4* p, const float4& v) {
    f32x4_v t; t.x = v.x; t.y = v.y; t.z = v.z; t.w = v.w;
    __builtin_nontemporal_store(t, reinterpret_cast<f32x4_v*>(p));
}

__device__ __forceinline__ void rot2(float& lo, float& hi, float a, float b) {
    float l = lo, h = hi;
    lo = fmaf(a, l,  b * h);   // top =  a*x0 + b*x1
    hi = fmaf(a, h, -b * l);   // bot = -b*x0 + a*x1
}

// Cross-lane xor-M partner fetch on the fastest pipe per M (R6/R8-validated).
template<int M>
__device__ __forceinline__ float pxor(float x, bool hi) {
    int xi = __float_as_int(x);
    if constexpr (M == 1)        // quad_perm [1,0,3,2]
        return __int_as_float(__builtin_amdgcn_update_dpp(0, xi, 0xB1, 0xF, 0xF, true));
    else if constexpr (M == 2)   // quad_perm [2,3,0,1]
        return __int_as_float(__builtin_amdgcn_update_dpp(0, xi, 0x4E, 0xF, 0xF, true));
    else if constexpr (M == 4)   // ds_swizzle BitMode xor 4
        return __int_as_float(__builtin_amdgcn_ds_swizzle(xi, 0x101F));
    else if constexpr (M == 8)   // row_ror:8 within row-of-16 == xor 8
        return __int_as_float(__builtin_amdgcn_update_dpp(0, xi, 0x128, 0xF, 0xF, true));
    else if constexpr (M == 16) {
#if HAVE_PL16
        unsigned xu = (unsigned)xi;
        auto r = __builtin_amdgcn_permlane16_swap(xu, xu, false, false);
        return __uint_as_float(hi ? r[0] : r[1]);
#else
        return __int_as_float(__builtin_amdgcn_ds_swizzle(xi, 0x401F));
#endif
    } else {                     // M == 32
#if HAVE_PL32
        unsigned xu = (unsigned)xi;
        auto r = __builtin_amdgcn_permlane32_swap(xu, xu, false, false);
        return __uint_as_float(hi ? r[0] : r[1]);
#else
        return __shfl_xor(x, 32, 64);
#endif
    }
}

// UNIF: c is wave-uniform -> readfirstlane so the compiler emits s_load (SMEM).
template<int M, int JSH, int LSH, bool UNIF>
__device__ __forceinline__ void shuf_layer(float4 (&v)[4], int lane, int base,
                                           const float* __restrict__ af,
                                           const float* __restrict__ bf) {
    const bool hi = (lane & M) != 0;
    #pragma unroll
    for (int j = 0; j < 4; ++j) {
        int c = base + (j << JSH) + (lane >> LSH);
        if constexpr (UNIF) c = __builtin_amdgcn_readfirstlane(c);
        const float a = af[c], b = bf[c];
        const float sb = hi ? -b : b;   // top: +b*partner ; bot: -b*partner
        v[j].x = fmaf(a, v[j].x, sb * pxor<M>(v[j].x, hi));
        v[j].y = fmaf(a, v[j].y, sb * pxor<M>(v[j].y, hi));
        v[j].z = fmaf(a, v[j].z, sb * pxor<M>(v[j].z, hi));
        v[j].w = fmaf(a, v[j].w, sb * pxor<M>(v[j].w, hi));
    }
}

__global__ __launch_bounds__(256, 7)
void bfly_kernel(const float* __restrict__ x,
                 const float* __restrict__ af,
                 const float* __restrict__ bf,
                 float* __restrict__ out) {
    const int lane = threadIdx.x & 63;
    const int q    = threadIdx.x >> 6;     // wave index = row quarter
    const size_t row = blockIdx.x;

    const float4* __restrict__ xr = reinterpret_cast<const float4*>(x + row * DIM) + q * 256;
    float4* __restrict__ orow     = reinterpret_cast<float4*>(out + row * DIM) + q * 256;

    __shared__ float4 xch[4][4][64];   // [wave][j][lane] = 16 KB

    float4 v[4];
    #pragma unroll
    for (int j = 0; j < 4; ++j) v[j] = xr[64 * j + lane];

    // ---- L0 (bs=1): pairs (x,y),(z,w); c0 = 512q + 128j + 2*lane, c0+1 ----
    #pragma unroll
    for (int j = 0; j < 4; ++j) {
        const int c = 512 * q + 128 * j + 2 * lane;
        float2 aa = *reinterpret_cast<const float2*>(af + c);
        float2 bb = *reinterpret_cast<const float2*>(bf + c);
        rot2(v[j].x, v[j].y, aa.x, bb.x);
        rot2(v[j].z, v[j].w, aa.y, bb.y);
    }

    // ---- L1 (bs=2): pairs (x,z),(y,w); c = 2048 + 256q + 64j + lane ----
    #pragma unroll
    for (int j = 0; j < 4; ++j) {
        const int c = 2048 + 256 * q + 64 * j + lane;
        const float a = af[c], b = bf[c];
        rot2(v[j].x, v[j].z, a, b);
        rot2(v[j].y, v[j].w, a, b);
    }

    // ---- L2..L7: cross-lane layers (DPP / swizzle / permlane) ----
    shuf_layer< 1, 5, 1, false>(v, lane, 3072 + 128 * q, af, bf);  // bs=4
    shuf_layer< 2, 4, 2, false>(v, lane, 3584 +  64 * q, af, bf);  // bs=8
    shuf_layer< 4, 3, 3, false>(v, lane, 3840 +  32 * q, af, bf);  // bs=16
    shuf_layer< 8, 2, 4, false>(v, lane, 3968 +  16 * q, af, bf);  // bs=32
    shuf_layer<16, 1, 5, false>(v, lane, 4032 +   8 * q, af, bf);  // bs=64
    shuf_layer<32, 0, 6, true >(v, lane, 4064 +   4 * q, af, bf);  // bs=128 (uniform)

    // ---- L8 (bs=256): pairs (0,1),(2,3); c = 4080 + 2q + k (uniform -> s_load) ----
    #pragma unroll
    for (int k = 0; k < 2; ++k) {
        const int c = __builtin_amdgcn_readfirstlane(4080 + 2 * q + k);
        const float a = af[c], b = bf[c];
        rot2(v[2*k].x, v[2*k+1].x, a, b);
        rot2(v[2*k].y, v[2*k+1].y, a, b);
        rot2(v[2*k].z, v[2*k+1].z, a, b);
        rot2(v[2*k].w, v[2*k+1].w, a, b);
    }
    // ---- L9 (bs=512): pairs (0,2),(1,3); c = 4088 + q (uniform) ----
    {
        const int c = __builtin_amdgcn_readfirstlane(4088 + q);
        const float a = af[c], b = bf[c];
        #pragma unroll
        for (int j = 0; j < 2; ++j) {
            rot2(v[j].x, v[j+2].x, a, b);
            rot2(v[j].y, v[j+2].y, a, b);
            rot2(v[j].z, v[j+2].z, a, b);
            rot2(v[j].w, v[j+2].w, a, b);
        }
    }

    // ---- L10+L11 fused: one 4-source combine across waves, ONE barrier ----
    // (R3/R6/R8-verified algebra.) u = w0*v + w1*v(q^1) + w2*v(q^2) + w3*v(q^3).
    {
        const float a0 = af[4092], b0 = bf[4092];   // e11=0  (constant idx -> s_load)
        const float a1 = af[4093], b1 = bf[4093];   // e11=1
        const float A  = af[4094], B  = bf[4094];
        const int h11 = q >> 1, h10 = q & 1;
        const float aO = h11 ? a1 : a0, bO = h11 ? b1 : b0;
        const float aX = h11 ? a0 : a1, bX = h11 ? b0 : b1;
        const float phX = h11 ? -B : B;
        const float w0 = A * aO;
        const float w1 = A * (h10 ? -bO : bO);
        const float w2 = phX * aX;
        const float w3 = phX * (h10 ? -bX : bX);
        const int q1 = q ^ 1, q2 = q ^ 2, q3 = q ^ 3;

        #pragma unroll
        for (int j = 0; j < 4; ++j) xch[q][j][lane] = v[j];
        __syncthreads();
        #pragma unroll
        for (int j = 0; j < 4; ++j) {
            float4 e1 = xch[q1][j][lane];
            float4 e2 = xch[q2][j][lane];
            float4 e3 = xch[q3][j][lane];
            float4 a;
            a.x = fmaf(w3, e3.x, fmaf(w2, e2.x, fmaf(w1, e1.x, w0 * v[j].x)));
            a.y = fmaf(w3, e3.y, fmaf(w2, e2.y, fmaf(w1, e1.y, w0 * v[j].y)));
            a.z = fmaf(w3, e3.z, fmaf(w2, e2.z, fmaf(w1, e1.z, w0 * v[j].z)));
            a.w = fmaf(w3, e3.w, fmaf(w2, e2.w, fmaf(w1, e1.w, w0 * v[j].w)));
            v[j] = a;
        }
    }

    // ---- Store: nontemporal, coalesced 16B/lane ----
    #pragma unroll
    for (int j = 0; j < 4; ++j) store_nt4(&orow[64 * j + lane], v[j]);
}

extern "C" void kernel_launch(void* const* d_in, const int* in_sizes, int n_in,
                              void* d_out, int out_size, void* d_ws, size_t ws_size,
                              hipStream_t stream) {
    const float* x  = (const float*)d_in[0];
    const float* af = (const float*)d_in[1];
    const float* bf = (const float*)d_in[2];
    float* out      = (float*)d_out;
    (void)d_ws; (void)ws_size;

    hipLaunchKernelGGL(bfly_kernel, dim3(BATCH), dim3(256), 0, stream,
                       x, af, bf, out);
}